// Round 2
// baseline (84.709 us; speedup 1.0000x reference)
//
#include <hip/hip_runtime.h>
#include <hip/hip_bf16.h>

#define NB 16384
#define NFEAT 32

__device__ __forceinline__ float cre(float x){
    float c = fminf(fmaxf(x, 0.0f), 127.0f/128.0f);
    return c + 0.1f*(x-c);
}

__global__ __launch_bounds__(64, 4) void nnue_fused(
    const int* __restrict__ indices,
    const int* __restrict__ offsets,
    const int* __restrict__ which_model,
    const float* __restrict__ embed,
    const float* __restrict__ main_bias,
    const float* __restrict__ vW1, const float* __restrict__ vb1,
    const float* __restrict__ vW2, const float* __restrict__ vb2,
    const float* __restrict__ vW3, const float* __restrict__ vb3,
    const float* __restrict__ pfW, const float* __restrict__ pfb,
    const float* __restrict__ ptW, const float* __restrict__ ptb,
    float* __restrict__ out0, float* __restrict__ out1, float* __restrict__ out2)
{
    const int l = threadIdx.x & 63;
    const int b = blockIdx.x;

    const int e    = __builtin_amdgcn_readfirstlane(which_model[b]);
    const int base = __builtin_amdgcn_readfirstlane(offsets[b]);
    const int g    = e >> 3;

    // ---- all 32 row indices up front (uniform -> s_load_dwordx4 x8) ----
    const int4* ip = reinterpret_cast<const int4*>(indices + base);
    int4 r0 = ip[0], r1 = ip[1], r2 = ip[2], r3 = ip[3];
    int4 r4 = ip[4], r5 = ip[5], r6 = ip[6], r7 = ip[7];
    int rows[32] = {r0.x,r0.y,r0.z,r0.w, r1.x,r1.y,r1.z,r1.w,
                    r2.x,r2.y,r2.z,r2.w, r3.x,r3.y,r3.z,r3.w,
                    r4.x,r4.y,r4.z,r4.w, r5.x,r5.y,r5.z,r5.w,
                    r6.x,r6.y,r6.z,r6.w, r7.x,r7.y,r7.z,r7.w};

    // ---- phase 1: gather-accumulate, 16 loads in flight ----
    float4 acc = *reinterpret_cast<const float4*>(main_bias + l*4);
    {
        float4 v[16];
        #pragma unroll
        for (int j=0;j<16;j++)
            v[j] = *reinterpret_cast<const float4*>(embed + (size_t)rows[j]*256 + l*4);
        #pragma unroll
        for (int j=0;j<16;j++){ acc.x+=v[j].x; acc.y+=v[j].y; acc.z+=v[j].z; acc.w+=v[j].w; }
        #pragma unroll
        for (int j=0;j<16;j++)
            v[j] = *reinterpret_cast<const float4*>(embed + (size_t)rows[16+j]*256 + l*4);
        #pragma unroll
        for (int j=0;j<16;j++){ acc.x+=v[j].x; acc.y+=v[j].y; acc.z+=v[j].z; acc.w+=v[j].w; }
    }
    const float psqt = __shfl(acc.x, 0);
    float4 embv;
    embv.x = cre(acc.x); embv.y = cre(acc.y); embv.z = cre(acc.z); embv.w = cre(acc.w);

    // ---- h1 = cre(vW1[e] @ emb + vb1[e]) : 16 outputs, K=256 ----
    float a1[16];
    {
        const float* w1 = vW1 + e*4096;
        #pragma unroll
        for (int h=0;h<2;h++){
            float4 w[8];
            #pragma unroll
            for (int k=0;k<8;k++)
                w[k] = *reinterpret_cast<const float4*>(w1 + (h*8+k)*256 + l*4);
            #pragma unroll
            for (int k=0;k<8;k++)
                a1[h*8+k] = w[k].x*embv.x + w[k].y*embv.y + w[k].z*embv.z + w[k].w*embv.w;
        }
    }
    // merge-butterfly: lane l ends with h1[l&15]
    #pragma unroll
    for (int i=0;i<8;i++){
        float give = (l&1) ? a1[2*i] : a1[2*i+1];
        float keep = (l&1) ? a1[2*i+1] : a1[2*i];
        a1[i] = keep + __shfl_xor(give, 1);
    }
    #pragma unroll
    for (int i=0;i<4;i++){
        float give = ((l>>1)&1) ? a1[2*i] : a1[2*i+1];
        float keep = ((l>>1)&1) ? a1[2*i+1] : a1[2*i];
        a1[i] = keep + __shfl_xor(give, 2);
    }
    #pragma unroll
    for (int i=0;i<2;i++){
        float give = ((l>>2)&1) ? a1[2*i] : a1[2*i+1];
        float keep = ((l>>2)&1) ? a1[2*i+1] : a1[2*i];
        a1[i] = keep + __shfl_xor(give, 4);
    }
    {
        float give = ((l>>3)&1) ? a1[0] : a1[1];
        float keep = ((l>>3)&1) ? a1[1] : a1[0];
        a1[0] = keep + __shfl_xor(give, 8);
    }
    a1[0] += __shfl_xor(a1[0], 16);
    a1[0] += __shfl_xor(a1[0], 32);
    const float h1v = cre(a1[0] + vb1[e*16 + (l&15)]);   // lane l holds h1[l&15]

    // ---- h2 : 32 outputs, K=16 ----
    float4 xh1;
    xh1.x = __shfl(h1v, (l&3)*4 + 0);
    xh1.y = __shfl(h1v, (l&3)*4 + 1);
    xh1.z = __shfl(h1v, (l&3)*4 + 2);
    xh1.w = __shfl(h1v, (l&3)*4 + 3);
    float a2[2];
    {
        float4 w0 = *reinterpret_cast<const float4*>(vW2 + e*512 + l*4);
        float4 w1 = *reinterpret_cast<const float4*>(vW2 + e*512 + 256 + l*4);
        a2[0] = w0.x*xh1.x + w0.y*xh1.y + w0.z*xh1.z + w0.w*xh1.w;
        a2[1] = w1.x*xh1.x + w1.y*xh1.y + w1.z*xh1.z + w1.w*xh1.w;
    }
    float v2;
    {
        float give = (l&1) ? a2[0] : a2[1];
        float keep = (l&1) ? a2[1] : a2[0];
        v2 = keep + __shfl_xor(give, 1);
        v2 += __shfl_xor(v2, 2);
    }
    const int o2 = ((l&1)<<4) + (l>>2);
    const float h2v = cre(v2 + vb2[e*32 + o2]);          // lane l holds h2[o2]

    // ---- value head ----
    const int i32 = l & 31;
    const int srcl = (i32 < 16) ? (4*i32) : (4*(i32-16)+1);
    const float h2full = __shfl(h2v, srcl);              // h2[l&31]
    float pv = vW3[e*32 + i32] * h2full;
    pv += __shfl_xor(pv, 1); pv += __shfl_xor(pv, 2); pv += __shfl_xor(pv, 4);
    pv += __shfl_xor(pv, 8); pv += __shfl_xor(pv, 16);
    if (l == 0) out0[b] = tanhf(pv + vb3[e] + psqt);

    // ---- policy heads: emb slices via shuffle of embv components ----
    const int sf = 4 + 4*g + (l&3);
    const int st = sf + 16;
    float4 xpf, xpt;
    xpf.x = __shfl(embv.x, sf); xpf.y = __shfl(embv.y, sf);
    xpf.z = __shfl(embv.z, sf); xpf.w = __shfl(embv.w, sf);
    xpt.x = __shfl(embv.x, st); xpt.y = __shfl(embv.y, st);
    xpt.z = __shfl(embv.z, st); xpt.w = __shfl(embv.w, st);
    float apf[4], apt[4];
    {
        float4 wf[4], wt[4];
        #pragma unroll
        for (int k=0;k<4;k++){
            wf[k] = *reinterpret_cast<const float4*>(pfW + e*1024 + k*256 + l*4);
            wt[k] = *reinterpret_cast<const float4*>(ptW + e*1024 + k*256 + l*4);
        }
        #pragma unroll
        for (int k=0;k<4;k++){
            apf[k] = wf[k].x*xpf.x + wf[k].y*xpf.y + wf[k].z*xpf.z + wf[k].w*xpf.w;
            apt[k] = wt[k].x*xpt.x + wt[k].y*xpt.y + wt[k].z*xpt.z + wt[k].w*xpt.w;
        }
    }
    #pragma unroll
    for (int i=0;i<2;i++){
        float give = (l&1) ? apf[2*i] : apf[2*i+1];
        float keep = (l&1) ? apf[2*i+1] : apf[2*i];
        apf[i] = keep + __shfl_xor(give, 1);
        give = (l&1) ? apt[2*i] : apt[2*i+1];
        keep = (l&1) ? apt[2*i+1] : apt[2*i];
        apt[i] = keep + __shfl_xor(give, 1);
    }
    float pfv, ptv;
    {
        float give = ((l>>1)&1) ? apf[0] : apf[1];
        float keep = ((l>>1)&1) ? apf[1] : apf[0];
        pfv = keep + __shfl_xor(give, 2);
        give = ((l>>1)&1) ? apt[0] : apt[1];
        keep = ((l>>1)&1) ? apt[1] : apt[0];
        ptv = keep + __shfl_xor(give, 2);
    }
    const int o = ((l&3)<<4) + (l>>2);
    out1[b*64 + o] = pfv + pfb[e*64 + o];
    out2[b*64 + o] = ptv + ptb[e*64 + o];
}

extern "C" void kernel_launch(void* const* d_in, const int* in_sizes, int n_in,
                              void* d_out, int out_size, void* d_ws, size_t ws_size,
                              hipStream_t stream) {
    const int*   indices = (const int*)d_in[0];
    const int*   offsets = (const int*)d_in[1];
    const int*   which   = (const int*)d_in[2];
    const float* embed   = (const float*)d_in[4];
    const float* mbias   = (const float*)d_in[5];
    const float* vW1 = (const float*)d_in[6];
    const float* vb1 = (const float*)d_in[7];
    const float* vW2 = (const float*)d_in[8];
    const float* vb2 = (const float*)d_in[9];
    const float* vW3 = (const float*)d_in[10];
    const float* vb3 = (const float*)d_in[11];
    const float* pfW = (const float*)d_in[12];
    const float* pfb = (const float*)d_in[13];
    const float* ptW = (const float*)d_in[14];
    const float* ptb = (const float*)d_in[15];
    float* out0 = (float*)d_out;
    float* out1 = out0 + NB;
    float* out2 = out1 + (size_t)NB*64;
    nnue_fused<<<NB, 64, 0, stream>>>(indices, offsets, which, embed, mbias,
        vW1, vb1, vW2, vb2, vW3, vb3, pfW, pfb, ptW, ptb, out0, out1, out2);
}

// Round 3
// 83.016 us; speedup vs baseline: 1.0204x; 1.0204x over previous
//
#include <hip/hip_runtime.h>
#include <hip/hip_bf16.h>

#define NB 16384
#define NFEAT 32

__device__ __forceinline__ float cre(float x){
    float c = fminf(fmaxf(x, 0.0f), 127.0f/128.0f);
    return c + 0.1f*(x-c);
}

#define SB() __builtin_amdgcn_sched_barrier(0)

__global__ __launch_bounds__(256, 4) void nnue_fused(
    const int* __restrict__ indices,
    const int* __restrict__ offsets,
    const int* __restrict__ which_model,
    const float* __restrict__ embed,
    const float* __restrict__ main_bias,
    const float* __restrict__ vW1, const float* __restrict__ vb1,
    const float* __restrict__ vW2, const float* __restrict__ vb2,
    const float* __restrict__ vW3, const float* __restrict__ vb3,
    const float* __restrict__ pfW, const float* __restrict__ pfb,
    const float* __restrict__ ptW, const float* __restrict__ ptb,
    float* __restrict__ out0, float* __restrict__ out1, float* __restrict__ out2)
{
    const int tid = threadIdx.x;
    const int l  = tid & 63;
    const int wv = tid >> 6;
    const int b  = (blockIdx.x << 2) + wv;

    const int e    = __builtin_amdgcn_readfirstlane(which_model[b]);
    const int base = __builtin_amdgcn_readfirstlane(offsets[b]);
    const int g    = e >> 3;

    // ---- all 32 row indices up front (uniform -> scalar loads) ----
    const int4* ip = reinterpret_cast<const int4*>(indices + base);
    int4 r0 = ip[0], r1 = ip[1], r2 = ip[2], r3 = ip[3];
    int4 r4 = ip[4], r5 = ip[5], r6 = ip[6], r7 = ip[7];
    int rows[32] = {r0.x,r0.y,r0.z,r0.w, r1.x,r1.y,r1.z,r1.w,
                    r2.x,r2.y,r2.z,r2.w, r3.x,r3.y,r3.z,r3.w,
                    r4.x,r4.y,r4.z,r4.w, r5.x,r5.y,r5.z,r5.w,
                    r6.x,r6.y,r6.z,r6.w, r7.x,r7.y,r7.z,r7.w};

    // ---- phase 1: gather-accumulate, software-pipelined 8+8 in flight ----
    float4 va[8], vb[8];
    float4 acc = *reinterpret_cast<const float4*>(main_bias + l*4);

    #pragma unroll
    for (int j=0;j<8;j++)
        va[j] = *reinterpret_cast<const float4*>(embed + (size_t)rows[j]*256 + l*4);
    SB();
    #pragma unroll
    for (int j=0;j<8;j++)
        vb[j] = *reinterpret_cast<const float4*>(embed + (size_t)rows[8+j]*256 + l*4);
    SB();
    #pragma unroll
    for (int j=0;j<8;j++){ acc.x+=va[j].x; acc.y+=va[j].y; acc.z+=va[j].z; acc.w+=va[j].w; }
    SB();
    #pragma unroll
    for (int j=0;j<8;j++)
        va[j] = *reinterpret_cast<const float4*>(embed + (size_t)rows[16+j]*256 + l*4);
    SB();
    #pragma unroll
    for (int j=0;j<8;j++){ acc.x+=vb[j].x; acc.y+=vb[j].y; acc.z+=vb[j].z; acc.w+=vb[j].w; }
    SB();
    #pragma unroll
    for (int j=0;j<8;j++)
        vb[j] = *reinterpret_cast<const float4*>(embed + (size_t)rows[24+j]*256 + l*4);
    SB();
    #pragma unroll
    for (int j=0;j<8;j++){ acc.x+=va[j].x; acc.y+=va[j].y; acc.z+=va[j].z; acc.w+=va[j].w; }
    SB();
    #pragma unroll
    for (int j=0;j<8;j++){ acc.x+=vb[j].x; acc.y+=vb[j].y; acc.z+=vb[j].z; acc.w+=vb[j].w; }

    const float psqt = __shfl(acc.x, 0);
    float4 embv;
    embv.x = cre(acc.x); embv.y = cre(acc.y); embv.z = cre(acc.z); embv.w = cre(acc.w);

    // ---- h1 = cre(vW1[e] @ emb + vb1[e]) : 16 outputs, K=256 ----
    float a1[16];
    {
        const float* w1 = vW1 + e*4096;
        float4 w[8];
        #pragma unroll
        for (int k=0;k<8;k++)
            w[k] = *reinterpret_cast<const float4*>(w1 + k*256 + l*4);
        SB();
        #pragma unroll
        for (int k=0;k<8;k++)
            va[k] = *reinterpret_cast<const float4*>(w1 + (8+k)*256 + l*4);
        SB();
        #pragma unroll
        for (int k=0;k<8;k++)
            a1[k] = w[k].x*embv.x + w[k].y*embv.y + w[k].z*embv.z + w[k].w*embv.w;
        SB();
        #pragma unroll
        for (int k=0;k<8;k++)
            a1[8+k] = va[k].x*embv.x + va[k].y*embv.y + va[k].z*embv.z + va[k].w*embv.w;
    }
    // merge-butterfly: lane l ends with h1[l&15]
    #pragma unroll
    for (int i=0;i<8;i++){
        float give = (l&1) ? a1[2*i] : a1[2*i+1];
        float keep = (l&1) ? a1[2*i+1] : a1[2*i];
        a1[i] = keep + __shfl_xor(give, 1);
    }
    #pragma unroll
    for (int i=0;i<4;i++){
        float give = ((l>>1)&1) ? a1[2*i] : a1[2*i+1];
        float keep = ((l>>1)&1) ? a1[2*i+1] : a1[2*i];
        a1[i] = keep + __shfl_xor(give, 2);
    }
    #pragma unroll
    for (int i=0;i<2;i++){
        float give = ((l>>2)&1) ? a1[2*i] : a1[2*i+1];
        float keep = ((l>>2)&1) ? a1[2*i+1] : a1[2*i];
        a1[i] = keep + __shfl_xor(give, 4);
    }
    {
        float give = ((l>>3)&1) ? a1[0] : a1[1];
        float keep = ((l>>3)&1) ? a1[1] : a1[0];
        a1[0] = keep + __shfl_xor(give, 8);
    }
    a1[0] += __shfl_xor(a1[0], 16);
    a1[0] += __shfl_xor(a1[0], 32);
    const float h1v = cre(a1[0] + vb1[e*16 + (l&15)]);   // lane l holds h1[l&15]

    // ---- issue all tail-layer weight loads together (10 loads in flight) ----
    float4 w2a, w2b, wf[4], wt[4];
    w2a = *reinterpret_cast<const float4*>(vW2 + e*512 + l*4);
    w2b = *reinterpret_cast<const float4*>(vW2 + e*512 + 256 + l*4);
    #pragma unroll
    for (int k=0;k<4;k++){
        wf[k] = *reinterpret_cast<const float4*>(pfW + e*1024 + k*256 + l*4);
        wt[k] = *reinterpret_cast<const float4*>(ptW + e*1024 + k*256 + l*4);
    }
    SB();

    // ---- h2 : 32 outputs, K=16 ----
    float4 xh1;
    xh1.x = __shfl(h1v, (l&3)*4 + 0);
    xh1.y = __shfl(h1v, (l&3)*4 + 1);
    xh1.z = __shfl(h1v, (l&3)*4 + 2);
    xh1.w = __shfl(h1v, (l&3)*4 + 3);
    float a2[2];
    a2[0] = w2a.x*xh1.x + w2a.y*xh1.y + w2a.z*xh1.z + w2a.w*xh1.w;
    a2[1] = w2b.x*xh1.x + w2b.y*xh1.y + w2b.z*xh1.z + w2b.w*xh1.w;
    float v2;
    {
        float give = (l&1) ? a2[0] : a2[1];
        float keep = (l&1) ? a2[1] : a2[0];
        v2 = keep + __shfl_xor(give, 1);
        v2 += __shfl_xor(v2, 2);
    }
    const int o2 = ((l&1)<<4) + (l>>2);
    const float h2v = cre(v2 + vb2[e*32 + o2]);          // lane l holds h2[o2]

    // ---- value head ----
    const int i32 = l & 31;
    const int srcl = (i32 < 16) ? (4*i32) : (4*(i32-16)+1);
    const float h2full = __shfl(h2v, srcl);              // h2[l&31]
    float pv = vW3[e*32 + i32] * h2full;
    pv += __shfl_xor(pv, 1); pv += __shfl_xor(pv, 2); pv += __shfl_xor(pv, 4);
    pv += __shfl_xor(pv, 8); pv += __shfl_xor(pv, 16);
    if (l == 0) out0[b] = tanhf(pv + vb3[e] + psqt);

    // ---- policy heads: emb slices via shuffle of embv components ----
    const int sf = 4 + 4*g + (l&3);
    const int st = sf + 16;
    float4 xpf, xpt;
    xpf.x = __shfl(embv.x, sf); xpf.y = __shfl(embv.y, sf);
    xpf.z = __shfl(embv.z, sf); xpf.w = __shfl(embv.w, sf);
    xpt.x = __shfl(embv.x, st); xpt.y = __shfl(embv.y, st);
    xpt.z = __shfl(embv.z, st); xpt.w = __shfl(embv.w, st);
    float apf[4], apt[4];
    #pragma unroll
    for (int k=0;k<4;k++){
        apf[k] = wf[k].x*xpf.x + wf[k].y*xpf.y + wf[k].z*xpf.z + wf[k].w*xpf.w;
        apt[k] = wt[k].x*xpt.x + wt[k].y*xpt.y + wt[k].z*xpt.z + wt[k].w*xpt.w;
    }
    #pragma unroll
    for (int i=0;i<2;i++){
        float give = (l&1) ? apf[2*i] : apf[2*i+1];
        float keep = (l&1) ? apf[2*i+1] : apf[2*i];
        apf[i] = keep + __shfl_xor(give, 1);
        give = (l&1) ? apt[2*i] : apt[2*i+1];
        keep = (l&1) ? apt[2*i+1] : apt[2*i];
        apt[i] = keep + __shfl_xor(give, 1);
    }
    float pfv, ptv;
    {
        float give = ((l>>1)&1) ? apf[0] : apf[1];
        float keep = ((l>>1)&1) ? apf[1] : apf[0];
        pfv = keep + __shfl_xor(give, 2);
        give = ((l>>1)&1) ? apt[0] : apt[1];
        keep = ((l>>1)&1) ? apt[1] : apt[0];
        ptv = keep + __shfl_xor(give, 2);
    }
    const int o = ((l&3)<<4) + (l>>2);
    out1[b*64 + o] = pfv + pfb[e*64 + o];
    out2[b*64 + o] = ptv + ptb[e*64 + o];
}

extern "C" void kernel_launch(void* const* d_in, const int* in_sizes, int n_in,
                              void* d_out, int out_size, void* d_ws, size_t ws_size,
                              hipStream_t stream) {
    const int*   indices = (const int*)d_in[0];
    const int*   offsets = (const int*)d_in[1];
    const int*   which   = (const int*)d_in[2];
    const float* embed   = (const float*)d_in[4];
    const float* mbias   = (const float*)d_in[5];
    const float* vW1 = (const float*)d_in[6];
    const float* vb1 = (const float*)d_in[7];
    const float* vW2 = (const float*)d_in[8];
    const float* vb2 = (const float*)d_in[9];
    const float* vW3 = (const float*)d_in[10];
    const float* vb3 = (const float*)d_in[11];
    const float* pfW = (const float*)d_in[12];
    const float* pfb = (const float*)d_in[13];
    const float* ptW = (const float*)d_in[14];
    const float* ptb = (const float*)d_in[15];
    float* out0 = (float*)d_out;
    float* out1 = out0 + NB;
    float* out2 = out1 + (size_t)NB*64;
    nnue_fused<<<NB/4, 256, 0, stream>>>(indices, offsets, which, embed, mbias,
        vW1, vb1, vW2, vb2, vW3, vb3, pfW, pfb, ptW, ptb, out0, out1, out2);
}

// Round 4
// 73.241 us; speedup vs baseline: 1.1566x; 1.1335x over previous
//
#include <hip/hip_runtime.h>
#include <hip/hip_fp16.h>

#define NB 16384
#define FEATC 106496
#define NFEAT 32

__device__ __forceinline__ float cre(float x){
    float c = fminf(fmaxf(x, 0.0f), 127.0f/128.0f);
    return c + 0.1f*(x-c);
}

#define SB() __builtin_amdgcn_sched_barrier(0)

// ---------------- fp32 -> fp16 table conversion (prepass) ----------------
__global__ __launch_bounds__(256) void convert_kernel(
    const float4* __restrict__ src, uint2* __restrict__ dst, int n4)
{
    int i = blockIdx.x*blockDim.x + threadIdx.x;
    const int stride = gridDim.x*blockDim.x;
    for (; i < n4; i += stride){
        float4 v = src[i];
        __half2 a = __floats2half2_rn(v.x, v.y);
        __half2 b = __floats2half2_rn(v.z, v.w);
        uint2 o;
        o.x = *reinterpret_cast<unsigned int*>(&a);
        o.y = *reinterpret_cast<unsigned int*>(&b);
        dst[i] = o;
    }
}

// ---------------- shared MLP tail (post-accumulate) ----------------
__device__ __forceinline__ void mlp_tail(
    float4 embv, float psqt, int e, int g, int l, int b,
    const float* __restrict__ vW1, const float* __restrict__ vb1,
    const float* __restrict__ vW2, const float* __restrict__ vb2,
    const float* __restrict__ vW3, const float* __restrict__ vb3,
    const float* __restrict__ pfW, const float* __restrict__ pfb,
    const float* __restrict__ ptW, const float* __restrict__ ptb,
    float* __restrict__ out0, float* __restrict__ out1, float* __restrict__ out2)
{
    // ---- h1 = cre(vW1[e] @ emb + vb1[e]) : 16 outputs, K=256 ----
    float a1[16];
    {
        const float* w1 = vW1 + e*4096;
        float4 w[8], w2[8];
        #pragma unroll
        for (int k=0;k<8;k++)
            w[k] = *reinterpret_cast<const float4*>(w1 + k*256 + l*4);
        SB();
        #pragma unroll
        for (int k=0;k<8;k++)
            w2[k] = *reinterpret_cast<const float4*>(w1 + (8+k)*256 + l*4);
        SB();
        #pragma unroll
        for (int k=0;k<8;k++)
            a1[k] = w[k].x*embv.x + w[k].y*embv.y + w[k].z*embv.z + w[k].w*embv.w;
        SB();
        #pragma unroll
        for (int k=0;k<8;k++)
            a1[8+k] = w2[k].x*embv.x + w2[k].y*embv.y + w2[k].z*embv.z + w2[k].w*embv.w;
    }
    // merge-butterfly: lane l ends with h1[l&15]
    #pragma unroll
    for (int i=0;i<8;i++){
        float give = (l&1) ? a1[2*i] : a1[2*i+1];
        float keep = (l&1) ? a1[2*i+1] : a1[2*i];
        a1[i] = keep + __shfl_xor(give, 1);
    }
    #pragma unroll
    for (int i=0;i<4;i++){
        float give = ((l>>1)&1) ? a1[2*i] : a1[2*i+1];
        float keep = ((l>>1)&1) ? a1[2*i+1] : a1[2*i];
        a1[i] = keep + __shfl_xor(give, 2);
    }
    #pragma unroll
    for (int i=0;i<2;i++){
        float give = ((l>>2)&1) ? a1[2*i] : a1[2*i+1];
        float keep = ((l>>2)&1) ? a1[2*i+1] : a1[2*i];
        a1[i] = keep + __shfl_xor(give, 4);
    }
    {
        float give = ((l>>3)&1) ? a1[0] : a1[1];
        float keep = ((l>>3)&1) ? a1[1] : a1[0];
        a1[0] = keep + __shfl_xor(give, 8);
    }
    a1[0] += __shfl_xor(a1[0], 16);
    a1[0] += __shfl_xor(a1[0], 32);
    const float h1v = cre(a1[0] + vb1[e*16 + (l&15)]);   // lane l holds h1[l&15]

    // ---- issue all tail-layer weight loads together ----
    float4 w2a, w2b, wf[4], wt[4];
    w2a = *reinterpret_cast<const float4*>(vW2 + e*512 + l*4);
    w2b = *reinterpret_cast<const float4*>(vW2 + e*512 + 256 + l*4);
    #pragma unroll
    for (int k=0;k<4;k++){
        wf[k] = *reinterpret_cast<const float4*>(pfW + e*1024 + k*256 + l*4);
        wt[k] = *reinterpret_cast<const float4*>(ptW + e*1024 + k*256 + l*4);
    }
    SB();

    // ---- h2 : 32 outputs, K=16 ----
    float4 xh1;
    xh1.x = __shfl(h1v, (l&3)*4 + 0);
    xh1.y = __shfl(h1v, (l&3)*4 + 1);
    xh1.z = __shfl(h1v, (l&3)*4 + 2);
    xh1.w = __shfl(h1v, (l&3)*4 + 3);
    float a2[2];
    a2[0] = w2a.x*xh1.x + w2a.y*xh1.y + w2a.z*xh1.z + w2a.w*xh1.w;
    a2[1] = w2b.x*xh1.x + w2b.y*xh1.y + w2b.z*xh1.z + w2b.w*xh1.w;
    float v2;
    {
        float give = (l&1) ? a2[0] : a2[1];
        float keep = (l&1) ? a2[1] : a2[0];
        v2 = keep + __shfl_xor(give, 1);
        v2 += __shfl_xor(v2, 2);
    }
    const int o2 = ((l&1)<<4) + (l>>2);
    const float h2v = cre(v2 + vb2[e*32 + o2]);          // lane l holds h2[o2]

    // ---- value head ----
    const int i32 = l & 31;
    const int srcl = (i32 < 16) ? (4*i32) : (4*(i32-16)+1);
    const float h2full = __shfl(h2v, srcl);              // h2[l&31]
    float pv = vW3[e*32 + i32] * h2full;
    pv += __shfl_xor(pv, 1); pv += __shfl_xor(pv, 2); pv += __shfl_xor(pv, 4);
    pv += __shfl_xor(pv, 8); pv += __shfl_xor(pv, 16);
    if (l == 0) out0[b] = tanhf(pv + vb3[e] + psqt);

    // ---- policy heads ----
    const int sf = 4 + 4*g + (l&3);
    const int st = sf + 16;
    float4 xpf, xpt;
    xpf.x = __shfl(embv.x, sf); xpf.y = __shfl(embv.y, sf);
    xpf.z = __shfl(embv.z, sf); xpf.w = __shfl(embv.w, sf);
    xpt.x = __shfl(embv.x, st); xpt.y = __shfl(embv.y, st);
    xpt.z = __shfl(embv.z, st); xpt.w = __shfl(embv.w, st);
    float apf[4], apt[4];
    #pragma unroll
    for (int k=0;k<4;k++){
        apf[k] = wf[k].x*xpf.x + wf[k].y*xpf.y + wf[k].z*xpf.z + wf[k].w*xpf.w;
        apt[k] = wt[k].x*xpt.x + wt[k].y*xpt.y + wt[k].z*xpt.z + wt[k].w*xpt.w;
    }
    #pragma unroll
    for (int i=0;i<2;i++){
        float give = (l&1) ? apf[2*i] : apf[2*i+1];
        float keep = (l&1) ? apf[2*i+1] : apf[2*i];
        apf[i] = keep + __shfl_xor(give, 1);
        give = (l&1) ? apt[2*i] : apt[2*i+1];
        keep = (l&1) ? apt[2*i+1] : apt[2*i];
        apt[i] = keep + __shfl_xor(give, 1);
    }
    float pfv, ptv;
    {
        float give = ((l>>1)&1) ? apf[0] : apf[1];
        float keep = ((l>>1)&1) ? apf[1] : apf[0];
        pfv = keep + __shfl_xor(give, 2);
        give = ((l>>1)&1) ? apt[0] : apt[1];
        keep = ((l>>1)&1) ? apt[1] : apt[0];
        ptv = keep + __shfl_xor(give, 2);
    }
    const int o = ((l&3)<<4) + (l>>2);
    out1[b*64 + o] = pfv + pfb[e*64 + o];
    out2[b*64 + o] = ptv + ptb[e*64 + o];
}

// ---------------- fused kernel, fp16 table ----------------
__global__ __launch_bounds__(256, 4) void nnue_fused_h(
    const int* __restrict__ indices,
    const int* __restrict__ offsets,
    const int* __restrict__ which_model,
    const __half* __restrict__ tab,
    const float* __restrict__ main_bias,
    const float* __restrict__ vW1, const float* __restrict__ vb1,
    const float* __restrict__ vW2, const float* __restrict__ vb2,
    const float* __restrict__ vW3, const float* __restrict__ vb3,
    const float* __restrict__ pfW, const float* __restrict__ pfb,
    const float* __restrict__ ptW, const float* __restrict__ ptb,
    float* __restrict__ out0, float* __restrict__ out1, float* __restrict__ out2)
{
    const int tid = threadIdx.x;
    const int l  = tid & 63;
    const int wv = tid >> 6;
    const int b  = (blockIdx.x << 2) + wv;

    const int e    = __builtin_amdgcn_readfirstlane(which_model[b]);
    const int base = __builtin_amdgcn_readfirstlane(offsets[b]);
    const int g    = e >> 3;

    const int4* ip = reinterpret_cast<const int4*>(indices + base);
    int4 r0 = ip[0], r1 = ip[1], r2 = ip[2], r3 = ip[3];
    int4 r4 = ip[4], r5 = ip[5], r6 = ip[6], r7 = ip[7];
    int rows[32] = {r0.x,r0.y,r0.z,r0.w, r1.x,r1.y,r1.z,r1.w,
                    r2.x,r2.y,r2.z,r2.w, r3.x,r3.y,r3.z,r3.w,
                    r4.x,r4.y,r4.z,r4.w, r5.x,r5.y,r5.z,r5.w,
                    r6.x,r6.y,r6.z,r6.w, r7.x,r7.y,r7.z,r7.w};

    // ---- gather-accumulate on fp16 rows (8 B/lane), 24-deep pipeline ----
    float4 acc = *reinterpret_cast<const float4*>(main_bias + l*4);
    uint2 va[8], vb[8], vc[8];
    #pragma unroll
    for (int j=0;j<8;j++)
        va[j] = *reinterpret_cast<const uint2*>(tab + (size_t)rows[j]*256 + l*4);
    SB();
    #pragma unroll
    for (int j=0;j<8;j++)
        vb[j] = *reinterpret_cast<const uint2*>(tab + (size_t)rows[8+j]*256 + l*4);
    SB();
    #pragma unroll
    for (int j=0;j<8;j++)
        vc[j] = *reinterpret_cast<const uint2*>(tab + (size_t)rows[16+j]*256 + l*4);
    SB();
    #pragma unroll
    for (int j=0;j<8;j++){
        float2 f0 = __half22float2(*reinterpret_cast<__half2*>(&va[j].x));
        float2 f1 = __half22float2(*reinterpret_cast<__half2*>(&va[j].y));
        acc.x += f0.x; acc.y += f0.y; acc.z += f1.x; acc.w += f1.y;
    }
    SB();
    #pragma unroll
    for (int j=0;j<8;j++)
        va[j] = *reinterpret_cast<const uint2*>(tab + (size_t)rows[24+j]*256 + l*4);
    SB();
    #pragma unroll
    for (int j=0;j<8;j++){
        float2 f0 = __half22float2(*reinterpret_cast<__half2*>(&vb[j].x));
        float2 f1 = __half22float2(*reinterpret_cast<__half2*>(&vb[j].y));
        acc.x += f0.x; acc.y += f0.y; acc.z += f1.x; acc.w += f1.y;
    }
    #pragma unroll
    for (int j=0;j<8;j++){
        float2 f0 = __half22float2(*reinterpret_cast<__half2*>(&vc[j].x));
        float2 f1 = __half22float2(*reinterpret_cast<__half2*>(&vc[j].y));
        acc.x += f0.x; acc.y += f0.y; acc.z += f1.x; acc.w += f1.y;
    }
    #pragma unroll
    for (int j=0;j<8;j++){
        float2 f0 = __half22float2(*reinterpret_cast<__half2*>(&va[j].x));
        float2 f1 = __half22float2(*reinterpret_cast<__half2*>(&va[j].y));
        acc.x += f0.x; acc.y += f0.y; acc.z += f1.x; acc.w += f1.y;
    }

    const float psqt = __shfl(acc.x, 0);
    float4 embv;
    embv.x = cre(acc.x); embv.y = cre(acc.y); embv.z = cre(acc.z); embv.w = cre(acc.w);

    mlp_tail(embv, psqt, e, g, l, b, vW1, vb1, vW2, vb2, vW3, vb3,
             pfW, pfb, ptW, ptb, out0, out1, out2);
}

// ---------------- fallback: fp32 table (round-3 path) ----------------
__global__ __launch_bounds__(256, 4) void nnue_fused_f(
    const int* __restrict__ indices,
    const int* __restrict__ offsets,
    const int* __restrict__ which_model,
    const float* __restrict__ embed,
    const float* __restrict__ main_bias,
    const float* __restrict__ vW1, const float* __restrict__ vb1,
    const float* __restrict__ vW2, const float* __restrict__ vb2,
    const float* __restrict__ vW3, const float* __restrict__ vb3,
    const float* __restrict__ pfW, const float* __restrict__ pfb,
    const float* __restrict__ ptW, const float* __restrict__ ptb,
    float* __restrict__ out0, float* __restrict__ out1, float* __restrict__ out2)
{
    const int tid = threadIdx.x;
    const int l  = tid & 63;
    const int wv = tid >> 6;
    const int b  = (blockIdx.x << 2) + wv;

    const int e    = __builtin_amdgcn_readfirstlane(which_model[b]);
    const int base = __builtin_amdgcn_readfirstlane(offsets[b]);
    const int g    = e >> 3;

    const int4* ip = reinterpret_cast<const int4*>(indices + base);
    int4 r0 = ip[0], r1 = ip[1], r2 = ip[2], r3 = ip[3];
    int4 r4 = ip[4], r5 = ip[5], r6 = ip[6], r7 = ip[7];
    int rows[32] = {r0.x,r0.y,r0.z,r0.w, r1.x,r1.y,r1.z,r1.w,
                    r2.x,r2.y,r2.z,r2.w, r3.x,r3.y,r3.z,r3.w,
                    r4.x,r4.y,r4.z,r4.w, r5.x,r5.y,r5.z,r5.w,
                    r6.x,r6.y,r6.z,r6.w, r7.x,r7.y,r7.z,r7.w};

    float4 va[8], vb[8];
    float4 acc = *reinterpret_cast<const float4*>(main_bias + l*4);
    #pragma unroll
    for (int j=0;j<8;j++)
        va[j] = *reinterpret_cast<const float4*>(embed + (size_t)rows[j]*256 + l*4);
    SB();
    #pragma unroll
    for (int j=0;j<8;j++)
        vb[j] = *reinterpret_cast<const float4*>(embed + (size_t)rows[8+j]*256 + l*4);
    SB();
    #pragma unroll
    for (int j=0;j<8;j++){ acc.x+=va[j].x; acc.y+=va[j].y; acc.z+=va[j].z; acc.w+=va[j].w; }
    SB();
    #pragma unroll
    for (int j=0;j<8;j++)
        va[j] = *reinterpret_cast<const float4*>(embed + (size_t)rows[16+j]*256 + l*4);
    SB();
    #pragma unroll
    for (int j=0;j<8;j++){ acc.x+=vb[j].x; acc.y+=vb[j].y; acc.z+=vb[j].z; acc.w+=vb[j].w; }
    SB();
    #pragma unroll
    for (int j=0;j<8;j++)
        vb[j] = *reinterpret_cast<const float4*>(embed + (size_t)rows[24+j]*256 + l*4);
    SB();
    #pragma unroll
    for (int j=0;j<8;j++){ acc.x+=va[j].x; acc.y+=va[j].y; acc.z+=va[j].z; acc.w+=va[j].w; }
    SB();
    #pragma unroll
    for (int j=0;j<8;j++){ acc.x+=vb[j].x; acc.y+=vb[j].y; acc.z+=vb[j].z; acc.w+=vb[j].w; }

    const float psqt = __shfl(acc.x, 0);
    float4 embv;
    embv.x = cre(acc.x); embv.y = cre(acc.y); embv.z = cre(acc.z); embv.w = cre(acc.w);

    mlp_tail(embv, psqt, e, g, l, b, vW1, vb1, vW2, vb2, vW3, vb3,
             pfW, pfb, ptW, ptb, out0, out1, out2);
}

extern "C" void kernel_launch(void* const* d_in, const int* in_sizes, int n_in,
                              void* d_out, int out_size, void* d_ws, size_t ws_size,
                              hipStream_t stream) {
    const int*   indices = (const int*)d_in[0];
    const int*   offsets = (const int*)d_in[1];
    const int*   which   = (const int*)d_in[2];
    const float* embed   = (const float*)d_in[4];
    const float* mbias   = (const float*)d_in[5];
    const float* vW1 = (const float*)d_in[6];
    const float* vb1 = (const float*)d_in[7];
    const float* vW2 = (const float*)d_in[8];
    const float* vb2 = (const float*)d_in[9];
    const float* vW3 = (const float*)d_in[10];
    const float* vb3 = (const float*)d_in[11];
    const float* pfW = (const float*)d_in[12];
    const float* pfb = (const float*)d_in[13];
    const float* ptW = (const float*)d_in[14];
    const float* ptb = (const float*)d_in[15];
    float* out0 = (float*)d_out;
    float* out1 = out0 + NB;
    float* out2 = out1 + (size_t)NB*64;

    const size_t need = (size_t)FEATC * 256 * sizeof(__half);
    if (ws_size >= need) {
        __half* tab = (__half*)d_ws;
        const int n4 = FEATC * 256 / 4;
        convert_kernel<<<2048, 256, 0, stream>>>(
            reinterpret_cast<const float4*>(embed), reinterpret_cast<uint2*>(tab), n4);
        nnue_fused_h<<<NB/4, 256, 0, stream>>>(indices, offsets, which, tab, mbias,
            vW1, vb1, vW2, vb2, vW3, vb3, pfW, pfb, ptW, ptb, out0, out1, out2);
    } else {
        nnue_fused_f<<<NB/4, 256, 0, stream>>>(indices, offsets, which, embed, mbias,
            vW1, vb1, vW2, vb2, vW3, vb3, pfW, pfb, ptW, ptb, out0, out1, out2);
    }
}

// Round 5
// 56.596 us; speedup vs baseline: 1.4967x; 1.2941x over previous
//
#include <hip/hip_runtime.h>
#include <hip/hip_fp16.h>

#define NB 16384
#define FEATC 106496
#define NFEAT 32
#define QSCALE (1.0f/2048.0f)
#define QINV   2048.0f

__device__ __forceinline__ float cre(float x){
    float c = fminf(fmaxf(x, 0.0f), 127.0f/128.0f);
    return c + 0.1f*(x-c);
}

#define SB() __builtin_amdgcn_sched_barrier(0)

// ---------------- fp32 -> int8 (scale 2^-11) table conversion ----------------
__global__ __launch_bounds__(256) void convert_i8(
    const float4* __restrict__ src, unsigned int* __restrict__ dst, int n4)
{
    int i = blockIdx.x*blockDim.x + threadIdx.x;
    const int stride = gridDim.x*blockDim.x;
    for (; i < n4; i += stride){
        float4 v = src[i];
        int a = __float2int_rn(fminf(fmaxf(v.x*QINV, -127.0f), 127.0f));
        int b = __float2int_rn(fminf(fmaxf(v.y*QINV, -127.0f), 127.0f));
        int c = __float2int_rn(fminf(fmaxf(v.z*QINV, -127.0f), 127.0f));
        int d = __float2int_rn(fminf(fmaxf(v.w*QINV, -127.0f), 127.0f));
        dst[i] = (a & 0xff) | ((b & 0xff) << 8) | ((c & 0xff) << 16) | ((d & 0xff) << 24);
    }
}

// ---------------- shared MLP tail (post-accumulate) ----------------
__device__ __forceinline__ void mlp_tail(
    float4 embv, float psqt, int e, int g, int l, int b,
    const float* __restrict__ vW1, const float* __restrict__ vb1,
    const float* __restrict__ vW2, const float* __restrict__ vb2,
    const float* __restrict__ vW3, const float* __restrict__ vb3,
    const float* __restrict__ pfW, const float* __restrict__ pfb,
    const float* __restrict__ ptW, const float* __restrict__ ptb,
    float* __restrict__ out0, float* __restrict__ out1, float* __restrict__ out2)
{
    // ---- h1 = cre(vW1[e] @ emb + vb1[e]) : 16 outputs, K=256 ----
    float a1[16];
    {
        const float* w1 = vW1 + e*4096;
        float4 w[8], w2[8];
        #pragma unroll
        for (int k=0;k<8;k++)
            w[k] = *reinterpret_cast<const float4*>(w1 + k*256 + l*4);
        SB();
        #pragma unroll
        for (int k=0;k<8;k++)
            w2[k] = *reinterpret_cast<const float4*>(w1 + (8+k)*256 + l*4);
        SB();
        #pragma unroll
        for (int k=0;k<8;k++)
            a1[k] = w[k].x*embv.x + w[k].y*embv.y + w[k].z*embv.z + w[k].w*embv.w;
        SB();
        #pragma unroll
        for (int k=0;k<8;k++)
            a1[8+k] = w2[k].x*embv.x + w2[k].y*embv.y + w2[k].z*embv.z + w2[k].w*embv.w;
    }
    // merge-butterfly: lane l ends with h1[l&15]
    #pragma unroll
    for (int i=0;i<8;i++){
        float give = (l&1) ? a1[2*i] : a1[2*i+1];
        float keep = (l&1) ? a1[2*i+1] : a1[2*i];
        a1[i] = keep + __shfl_xor(give, 1);
    }
    #pragma unroll
    for (int i=0;i<4;i++){
        float give = ((l>>1)&1) ? a1[2*i] : a1[2*i+1];
        float keep = ((l>>1)&1) ? a1[2*i+1] : a1[2*i];
        a1[i] = keep + __shfl_xor(give, 2);
    }
    #pragma unroll
    for (int i=0;i<2;i++){
        float give = ((l>>2)&1) ? a1[2*i] : a1[2*i+1];
        float keep = ((l>>2)&1) ? a1[2*i+1] : a1[2*i];
        a1[i] = keep + __shfl_xor(give, 4);
    }
    {
        float give = ((l>>3)&1) ? a1[0] : a1[1];
        float keep = ((l>>3)&1) ? a1[1] : a1[0];
        a1[0] = keep + __shfl_xor(give, 8);
    }
    a1[0] += __shfl_xor(a1[0], 16);
    a1[0] += __shfl_xor(a1[0], 32);
    const float h1v = cre(a1[0] + vb1[e*16 + (l&15)]);   // lane l holds h1[l&15]

    // ---- issue all tail-layer weight loads together ----
    float4 w2a, w2b, wf[4], wt[4];
    w2a = *reinterpret_cast<const float4*>(vW2 + e*512 + l*4);
    w2b = *reinterpret_cast<const float4*>(vW2 + e*512 + 256 + l*4);
    #pragma unroll
    for (int k=0;k<4;k++){
        wf[k] = *reinterpret_cast<const float4*>(pfW + e*1024 + k*256 + l*4);
        wt[k] = *reinterpret_cast<const float4*>(ptW + e*1024 + k*256 + l*4);
    }
    SB();

    // ---- h2 : 32 outputs, K=16 ----
    float4 xh1;
    xh1.x = __shfl(h1v, (l&3)*4 + 0);
    xh1.y = __shfl(h1v, (l&3)*4 + 1);
    xh1.z = __shfl(h1v, (l&3)*4 + 2);
    xh1.w = __shfl(h1v, (l&3)*4 + 3);
    float a2[2];
    a2[0] = w2a.x*xh1.x + w2a.y*xh1.y + w2a.z*xh1.z + w2a.w*xh1.w;
    a2[1] = w2b.x*xh1.x + w2b.y*xh1.y + w2b.z*xh1.z + w2b.w*xh1.w;
    float v2;
    {
        float give = (l&1) ? a2[0] : a2[1];
        float keep = (l&1) ? a2[1] : a2[0];
        v2 = keep + __shfl_xor(give, 1);
        v2 += __shfl_xor(v2, 2);
    }
    const int o2 = ((l&1)<<4) + (l>>2);
    const float h2v = cre(v2 + vb2[e*32 + o2]);          // lane l holds h2[o2]

    // ---- value head ----
    const int i32 = l & 31;
    const int srcl = (i32 < 16) ? (4*i32) : (4*(i32-16)+1);
    const float h2full = __shfl(h2v, srcl);              // h2[l&31]
    float pv = vW3[e*32 + i32] * h2full;
    pv += __shfl_xor(pv, 1); pv += __shfl_xor(pv, 2); pv += __shfl_xor(pv, 4);
    pv += __shfl_xor(pv, 8); pv += __shfl_xor(pv, 16);
    if (l == 0) out0[b] = tanhf(pv + vb3[e] + psqt);

    // ---- policy heads ----
    const int sf = 4 + 4*g + (l&3);
    const int st = sf + 16;
    float4 xpf, xpt;
    xpf.x = __shfl(embv.x, sf); xpf.y = __shfl(embv.y, sf);
    xpf.z = __shfl(embv.z, sf); xpf.w = __shfl(embv.w, sf);
    xpt.x = __shfl(embv.x, st); xpt.y = __shfl(embv.y, st);
    xpt.z = __shfl(embv.z, st); xpt.w = __shfl(embv.w, st);
    float apf[4], apt[4];
    #pragma unroll
    for (int k=0;k<4;k++){
        apf[k] = wf[k].x*xpf.x + wf[k].y*xpf.y + wf[k].z*xpf.z + wf[k].w*xpf.w;
        apt[k] = wt[k].x*xpt.x + wt[k].y*xpt.y + wt[k].z*xpt.z + wt[k].w*xpt.w;
    }
    #pragma unroll
    for (int i=0;i<2;i++){
        float give = (l&1) ? apf[2*i] : apf[2*i+1];
        float keep = (l&1) ? apf[2*i+1] : apf[2*i];
        apf[i] = keep + __shfl_xor(give, 1);
        give = (l&1) ? apt[2*i] : apt[2*i+1];
        keep = (l&1) ? apt[2*i+1] : apt[2*i];
        apt[i] = keep + __shfl_xor(give, 1);
    }
    float pfv, ptv;
    {
        float give = ((l>>1)&1) ? apf[0] : apf[1];
        float keep = ((l>>1)&1) ? apf[1] : apf[0];
        pfv = keep + __shfl_xor(give, 2);
        give = ((l>>1)&1) ? apt[0] : apt[1];
        keep = ((l>>1)&1) ? apt[1] : apt[0];
        ptv = keep + __shfl_xor(give, 2);
    }
    const int o = ((l&3)<<4) + (l>>2);
    out1[b*64 + o] = pfv + pfb[e*64 + o];
    out2[b*64 + o] = ptv + ptb[e*64 + o];
}

// ---------------- fused kernel, int8 table ----------------
__global__ __launch_bounds__(256, 4) void nnue_fused_q(
    const int* __restrict__ indices,
    const int* __restrict__ offsets,
    const int* __restrict__ which_model,
    const unsigned char* __restrict__ tab,
    const float* __restrict__ main_bias,
    const float* __restrict__ vW1, const float* __restrict__ vb1,
    const float* __restrict__ vW2, const float* __restrict__ vb2,
    const float* __restrict__ vW3, const float* __restrict__ vb3,
    const float* __restrict__ pfW, const float* __restrict__ pfb,
    const float* __restrict__ ptW, const float* __restrict__ ptb,
    float* __restrict__ out0, float* __restrict__ out1, float* __restrict__ out2)
{
    const int tid = threadIdx.x;
    const int l  = tid & 63;
    const int wv = tid >> 6;
    const int b  = (blockIdx.x << 2) + wv;

    const int e    = __builtin_amdgcn_readfirstlane(which_model[b]);
    const int base = __builtin_amdgcn_readfirstlane(offsets[b]);
    const int g    = e >> 3;

    const int4* ip = reinterpret_cast<const int4*>(indices + base);
    int4 r0 = ip[0], r1 = ip[1], r2 = ip[2], r3 = ip[3];
    int4 r4 = ip[4], r5 = ip[5], r6 = ip[6], r7 = ip[7];
    int rows[32] = {r0.x,r0.y,r0.z,r0.w, r1.x,r1.y,r1.z,r1.w,
                    r2.x,r2.y,r2.z,r2.w, r3.x,r3.y,r3.z,r3.w,
                    r4.x,r4.y,r4.z,r4.w, r5.x,r5.y,r5.z,r5.w,
                    r6.x,r6.y,r6.z,r6.w, r7.x,r7.y,r7.z,r7.w};

    // ---- gather-accumulate on int8 rows (4 B/lane), exact int32 accum ----
    int s0=0, s1=0, s2=0, s3=0;
    unsigned int va[8], vb[8], vc[8];
    #pragma unroll
    for (int j=0;j<8;j++)
        va[j] = *reinterpret_cast<const unsigned int*>(tab + (size_t)rows[j]*256 + l*4);
    SB();
    #pragma unroll
    for (int j=0;j<8;j++)
        vb[j] = *reinterpret_cast<const unsigned int*>(tab + (size_t)rows[8+j]*256 + l*4);
    SB();
    #pragma unroll
    for (int j=0;j<8;j++)
        vc[j] = *reinterpret_cast<const unsigned int*>(tab + (size_t)rows[16+j]*256 + l*4);
    SB();
    #pragma unroll
    for (int j=0;j<8;j++){
        unsigned int w = va[j];
        s0 += (int)(w << 24) >> 24;
        s1 += (int)(w << 16) >> 24;
        s2 += (int)(w <<  8) >> 24;
        s3 += (int)w >> 24;
    }
    SB();
    #pragma unroll
    for (int j=0;j<8;j++)
        va[j] = *reinterpret_cast<const unsigned int*>(tab + (size_t)rows[24+j]*256 + l*4);
    SB();
    #pragma unroll
    for (int j=0;j<8;j++){
        unsigned int w = vb[j];
        s0 += (int)(w << 24) >> 24;
        s1 += (int)(w << 16) >> 24;
        s2 += (int)(w <<  8) >> 24;
        s3 += (int)w >> 24;
    }
    #pragma unroll
    for (int j=0;j<8;j++){
        unsigned int w = vc[j];
        s0 += (int)(w << 24) >> 24;
        s1 += (int)(w << 16) >> 24;
        s2 += (int)(w <<  8) >> 24;
        s3 += (int)w >> 24;
    }
    #pragma unroll
    for (int j=0;j<8;j++){
        unsigned int w = va[j];
        s0 += (int)(w << 24) >> 24;
        s1 += (int)(w << 16) >> 24;
        s2 += (int)(w <<  8) >> 24;
        s3 += (int)w >> 24;
    }

    const float4 bias = *reinterpret_cast<const float4*>(main_bias + l*4);
    float4 acc;
    acc.x = (float)s0 * QSCALE + bias.x;
    acc.y = (float)s1 * QSCALE + bias.y;
    acc.z = (float)s2 * QSCALE + bias.z;
    acc.w = (float)s3 * QSCALE + bias.w;

    const float psqt = __shfl(acc.x, 0);
    float4 embv;
    embv.x = cre(acc.x); embv.y = cre(acc.y); embv.z = cre(acc.z); embv.w = cre(acc.w);

    mlp_tail(embv, psqt, e, g, l, b, vW1, vb1, vW2, vb2, vW3, vb3,
             pfW, pfb, ptW, ptb, out0, out1, out2);
}

// ---------------- fallback: fp32 table (round-3 path) ----------------
__global__ __launch_bounds__(256, 4) void nnue_fused_f(
    const int* __restrict__ indices,
    const int* __restrict__ offsets,
    const int* __restrict__ which_model,
    const float* __restrict__ embed,
    const float* __restrict__ main_bias,
    const float* __restrict__ vW1, const float* __restrict__ vb1,
    const float* __restrict__ vW2, const float* __restrict__ vb2,
    const float* __restrict__ vW3, const float* __restrict__ vb3,
    const float* __restrict__ pfW, const float* __restrict__ pfb,
    const float* __restrict__ ptW, const float* __restrict__ ptb,
    float* __restrict__ out0, float* __restrict__ out1, float* __restrict__ out2)
{
    const int tid = threadIdx.x;
    const int l  = tid & 63;
    const int wv = tid >> 6;
    const int b  = (blockIdx.x << 2) + wv;

    const int e    = __builtin_amdgcn_readfirstlane(which_model[b]);
    const int base = __builtin_amdgcn_readfirstlane(offsets[b]);
    const int g    = e >> 3;

    const int4* ip = reinterpret_cast<const int4*>(indices + base);
    int4 r0 = ip[0], r1 = ip[1], r2 = ip[2], r3 = ip[3];
    int4 r4 = ip[4], r5 = ip[5], r6 = ip[6], r7 = ip[7];
    int rows[32] = {r0.x,r0.y,r0.z,r0.w, r1.x,r1.y,r1.z,r1.w,
                    r2.x,r2.y,r2.z,r2.w, r3.x,r3.y,r3.z,r3.w,
                    r4.x,r4.y,r4.z,r4.w, r5.x,r5.y,r5.z,r5.w,
                    r6.x,r6.y,r6.z,r6.w, r7.x,r7.y,r7.z,r7.w};

    float4 va[8], vb[8];
    float4 acc = *reinterpret_cast<const float4*>(main_bias + l*4);
    #pragma unroll
    for (int j=0;j<8;j++)
        va[j] = *reinterpret_cast<const float4*>(embed + (size_t)rows[j]*256 + l*4);
    SB();
    #pragma unroll
    for (int j=0;j<8;j++)
        vb[j] = *reinterpret_cast<const float4*>(embed + (size_t)rows[8+j]*256 + l*4);
    SB();
    #pragma unroll
    for (int j=0;j<8;j++){ acc.x+=va[j].x; acc.y+=va[j].y; acc.z+=va[j].z; acc.w+=va[j].w; }
    SB();
    #pragma unroll
    for (int j=0;j<8;j++)
        va[j] = *reinterpret_cast<const float4*>(embed + (size_t)rows[16+j]*256 + l*4);
    SB();
    #pragma unroll
    for (int j=0;j<8;j++){ acc.x+=vb[j].x; acc.y+=vb[j].y; acc.z+=vb[j].z; acc.w+=vb[j].w; }
    SB();
    #pragma unroll
    for (int j=0;j<8;j++)
        vb[j] = *reinterpret_cast<const float4*>(embed + (size_t)rows[24+j]*256 + l*4);
    SB();
    #pragma unroll
    for (int j=0;j<8;j++){ acc.x+=va[j].x; acc.y+=va[j].y; acc.z+=va[j].z; acc.w+=va[j].w; }
    SB();
    #pragma unroll
    for (int j=0;j<8;j++){ acc.x+=vb[j].x; acc.y+=vb[j].y; acc.z+=vb[j].z; acc.w+=vb[j].w; }

    const float psqt = __shfl(acc.x, 0);
    float4 embv;
    embv.x = cre(acc.x); embv.y = cre(acc.y); embv.z = cre(acc.z); embv.w = cre(acc.w);

    mlp_tail(embv, psqt, e, g, l, b, vW1, vb1, vW2, vb2, vW3, vb3,
             pfW, pfb, ptW, ptb, out0, out1, out2);
}

extern "C" void kernel_launch(void* const* d_in, const int* in_sizes, int n_in,
                              void* d_out, int out_size, void* d_ws, size_t ws_size,
                              hipStream_t stream) {
    const int*   indices = (const int*)d_in[0];
    const int*   offsets = (const int*)d_in[1];
    const int*   which   = (const int*)d_in[2];
    const float* embed   = (const float*)d_in[4];
    const float* mbias   = (const float*)d_in[5];
    const float* vW1 = (const float*)d_in[6];
    const float* vb1 = (const float*)d_in[7];
    const float* vW2 = (const float*)d_in[8];
    const float* vb2 = (const float*)d_in[9];
    const float* vW3 = (const float*)d_in[10];
    const float* vb3 = (const float*)d_in[11];
    const float* pfW = (const float*)d_in[12];
    const float* pfb = (const float*)d_in[13];
    const float* ptW = (const float*)d_in[14];
    const float* ptb = (const float*)d_in[15];
    float* out0 = (float*)d_out;
    float* out1 = out0 + NB;
    float* out2 = out1 + (size_t)NB*64;

    const size_t need = (size_t)FEATC * 256;
    if (ws_size >= need) {
        unsigned char* tab = (unsigned char*)d_ws;
        const int n4 = FEATC * 256 / 4;
        convert_i8<<<2048, 256, 0, stream>>>(
            reinterpret_cast<const float4*>(embed), reinterpret_cast<unsigned int*>(tab), n4);
        nnue_fused_q<<<NB/4, 256, 0, stream>>>(indices, offsets, which, tab, mbias,
            vW1, vb1, vW2, vb2, vW3, vb3, pfW, pfb, ptW, ptb, out0, out1, out2);
    } else {
        nnue_fused_f<<<NB/4, 256, 0, stream>>>(indices, offsets, which, embed, mbias,
            vW1, vb1, vW2, vb2, vW3, vb3, pfW, pfb, ptW, ptb, out0, out1, out2);
    }
}